// Round 1
// baseline (451.087 us; speedup 1.0000x reference)
//
#include <hip/hip_runtime.h>

typedef __bf16 bf16_t;
typedef __bf16 bf16x8 __attribute__((ext_vector_type(8)));
typedef __bf16 bf16x4 __attribute__((ext_vector_type(4)));
typedef float  f32x4  __attribute__((ext_vector_type(4)));

#define MFMA16(a,b,c) __builtin_amdgcn_mfma_f32_16x16x32_bf16((a),(b),(c),0,0,0)

__device__ __forceinline__ void gl_lds16(const void* g, void* l) {
    __builtin_amdgcn_global_load_lds(
        (__attribute__((address_space(1))) void*)(g),
        (__attribute__((address_space(3))) void*)(l),
        16, 0, 0);
}

// ---------------- problem constants ----------------
// B=2 S=4096 D=2048 HQ=32 HK=HV=8 H=32 DK=DV=64 CHUNK=64 NC=64 QKV=3072 OUT=2048
static constexpr int S_TOT   = 8192;      // B*S rows
static constexpr int D_IN    = 2048;
static constexpr int QKV     = 3072;
static constexpr int OUT_D   = 2048;
static constexpr int NCHUNK  = 64;

// ---------------- fp32 -> bf16 convert (vectorized) ----------------
__global__ __launch_bounds__(256)
void cvt_f32_bf16(const float* __restrict__ in, bf16_t* __restrict__ out) {
    int i = blockIdx.x * 256 + threadIdx.x;
    f32x4 v = ((const f32x4*)in)[i];
    bf16x4 o;
    o[0] = (bf16_t)v[0]; o[1] = (bf16_t)v[1]; o[2] = (bf16_t)v[2]; o[3] = (bf16_t)v[3];
    ((bf16x4*)out)[i] = o;
}

// ---------------- fp32 [R][C] -> bf16 [C][R] transpose ----------------
__global__ __launch_bounds__(256)
void transpose_f32_bf16(const float* __restrict__ in, bf16_t* __restrict__ out, int R, int C) {
    __shared__ float tile[64][65];
    const int t  = threadIdx.x;
    const int r0 = blockIdx.y * 64, c0 = blockIdx.x * 64;
#pragma unroll
    for (int p = 0; p < 4; p++) {
        int row = p * 16 + (t >> 4);
        int col = (t & 15) * 4;
        f32x4 v = *(const f32x4*)&in[(size_t)(r0 + row) * C + c0 + col];
        tile[row][col + 0] = v[0]; tile[row][col + 1] = v[1];
        tile[row][col + 2] = v[2]; tile[row][col + 3] = v[3];
    }
    __syncthreads();
#pragma unroll
    for (int p = 0; p < 4; p++) {
        int oc  = p * 16 + (t >> 4);   // input col == output row
        int orr = (t & 15) * 4;        // input row == output col
        bf16x4 v;
        v[0] = (bf16_t)tile[orr + 0][oc]; v[1] = (bf16_t)tile[orr + 1][oc];
        v[2] = (bf16_t)tile[orr + 2][oc]; v[3] = (bf16_t)tile[orr + 3][oc];
        *(bf16x4*)&out[(size_t)(c0 + oc) * R + r0 + orr] = v;
    }
}

// ---------------- m97-style GEMM: C[M][N] = A[M][K] * Bt[N][K]^T ----------------
template<int OUT_BF16>
__global__ __launch_bounds__(256)
void gemm_bt(const bf16_t* __restrict__ A, const bf16_t* __restrict__ Bt,
             void* __restrict__ Cout, int M, int N, int K) {
    __shared__ alignas(16) bf16_t lA[128 * 32];
    __shared__ alignas(16) bf16_t lB[128 * 32];
    const int tid = threadIdx.x;
    const int m0 = blockIdx.y * 128;
    const int n0 = blockIdx.x * 128;
    const int w = tid >> 6, lane = tid & 63;
    const int wr = (w >> 1) * 64, wc = (w & 1) * 64;
    const int l15 = lane & 15, q8 = (lane >> 4) * 8, q4 = (lane >> 4) * 4;
    f32x4 acc[4][4] = {};
    const bf16_t* Ag = A + (size_t)(m0 + (tid >> 2)) * K + (tid & 3) * 8;
    const bf16_t* Bg = Bt + (size_t)(n0 + (tid >> 2)) * K + (tid & 3) * 8;
    const size_t rowStep = (size_t)64 * K;
    bf16_t* lA_t = lA + tid * 8;
    bf16_t* lB_t = lB + tid * 8;
    for (int k0 = 0; k0 < K; k0 += 32) {
        gl_lds16(Ag + k0,           lA_t);
        gl_lds16(Ag + k0 + rowStep, lA_t + 64 * 32);
        gl_lds16(Bg + k0,           lB_t);
        gl_lds16(Bg + k0 + rowStep, lB_t + 64 * 32);
        __syncthreads();
        bf16x8 af[4], bf_[4];
#pragma unroll
        for (int mi = 0; mi < 4; mi++) af[mi]  = *(const bf16x8*)&lA[(wr + mi * 16 + l15) * 32 + q8];
#pragma unroll
        for (int nj = 0; nj < 4; nj++) bf_[nj] = *(const bf16x8*)&lB[(wc + nj * 16 + l15) * 32 + q8];
#pragma unroll
        for (int mi = 0; mi < 4; mi++)
#pragma unroll
            for (int nj = 0; nj < 4; nj++)
                acc[mi][nj] = MFMA16(af[mi], bf_[nj], acc[mi][nj]);
        __syncthreads();
    }
    if (OUT_BF16) {
        bf16_t* C = (bf16_t*)Cout;
#pragma unroll
        for (int mi = 0; mi < 4; mi++)
#pragma unroll
            for (int nj = 0; nj < 4; nj++)
#pragma unroll
                for (int r = 0; r < 4; r++)
                    C[(size_t)(m0 + wr + mi * 16 + q4 + r) * N + n0 + wc + nj * 16 + l15] =
                        (bf16_t)acc[mi][nj][r];
    } else {
        float* C = (float*)Cout;
#pragma unroll
        for (int mi = 0; mi < 4; mi++)
#pragma unroll
            for (int nj = 0; nj < 4; nj++)
#pragma unroll
                for (int r = 0; r < 4; r++)
                    C[(size_t)(m0 + wr + mi * 16 + q4 + r) * N + n0 + wc + nj * 16 + l15] =
                        acc[mi][nj][r];
    }
}

// ---------------- phase A: Zc[b][hk][c][dv][dk] = sum_tok v[tok][dv]*k[tok][dk] ----------------
__global__ __launch_bounds__(64)
void chunk_kv(const bf16_t* __restrict__ proj, float* __restrict__ Zc) {
    const int idx = blockIdx.x;               // ((b*8+hk)*64 + c)
    const int c = idx & 63, hk = (idx >> 6) & 7, b = idx >> 9;
    const int tokBase = b * 4096 + c * 64;
    __shared__ alignas(16) bf16_t kT[64 * 64];   // [dk][tok]
    __shared__ alignas(16) bf16_t vT[64 * 64];   // [dv][tok]
    const int lane = threadIdx.x;
    const bf16_t* kg = proj + (size_t)tokBase * QKV + 2048 + hk * 64;
    const bf16_t* vg = proj + (size_t)tokBase * QKV + 2560 + hk * 64;
#pragma unroll
    for (int p = 0; p < 8; p++) {
        int tok = p * 8 + (lane >> 3);
        int d0  = (lane & 7) * 8;
        bf16x8 kv = *(const bf16x8*)&kg[(size_t)tok * QKV + d0];
        bf16x8 vv = *(const bf16x8*)&vg[(size_t)tok * QKV + d0];
#pragma unroll
        for (int e = 0; e < 8; e++) {
            kT[(d0 + e) * 64 + tok] = kv[e];
            vT[(d0 + e) * 64 + tok] = vv[e];
        }
    }
    __syncthreads();
    const int l15 = lane & 15, q8 = (lane >> 4) * 8, q4 = (lane >> 4) * 4;
    f32x4 acc[4][4] = {};
#pragma unroll
    for (int ks = 0; ks < 2; ks++) {
        bf16x8 af[4], bf_[4];
#pragma unroll
        for (int mi = 0; mi < 4; mi++) af[mi]  = *(const bf16x8*)&vT[(mi * 16 + l15) * 64 + ks * 32 + q8];
#pragma unroll
        for (int nj = 0; nj < 4; nj++) bf_[nj] = *(const bf16x8*)&kT[(nj * 16 + l15) * 64 + ks * 32 + q8];
#pragma unroll
        for (int mi = 0; mi < 4; mi++)
#pragma unroll
            for (int nj = 0; nj < 4; nj++)
                acc[mi][nj] = MFMA16(af[mi], bf_[nj], acc[mi][nj]);
    }
    float* zout = Zc + (size_t)idx * 4096;
#pragma unroll
    for (int mi = 0; mi < 4; mi++)
#pragma unroll
        for (int nj = 0; nj < 4; nj++)
#pragma unroll
            for (int r = 0; r < 4; r++)
                zout[(mi * 16 + q4 + r) * 64 + nj * 16 + l15] = acc[mi][nj][r];
}

// ---------------- phase B: per-q-head prefix state (bf16) + final state out ----------------
__global__ __launch_bounds__(256)
void prefix_state(const float* __restrict__ Zc, const float* __restrict__ S0,
                  bf16_t* __restrict__ Zp, float* __restrict__ SfOut) {
    const int slice = blockIdx.x & 15;
    const int bh = blockIdx.x >> 4;
    const int h = bh & 31, b = bh >> 5;
    const int hk = h >> 2;
    const int e = slice * 256 + threadIdx.x;      // 0..4095, e = dv*64 + dk
    const int dv = e >> 6, dk = e & 63;
    float acc = S0[(size_t)b * 131072 + h * 4096 + dk * 64 + dv];   // S0[b][h][dk][dv]
    const float* zc = Zc + ((size_t)(b * 8 + hk) * 64) * 4096 + e;
    bf16_t* zp = Zp + ((size_t)(b * 32 + h) * 64) * 4096 + e;
    for (int c = 0; c < NCHUNK; c++) {
        zp[(size_t)c * 4096] = (bf16_t)acc;     // prefix EXCLUDING chunk c
        acc += zc[(size_t)c * 4096];
    }
    SfOut[(size_t)b * 131072 + h * 4096 + dk * 64 + dv] = acc;
}

// ---------------- phase C: o = mask(q k^T) v + q * Zp^T ----------------
__global__ __launch_bounds__(64)
void attn_chunk(const bf16_t* __restrict__ proj, const bf16_t* __restrict__ Zp,
                bf16_t* __restrict__ O) {
    const int idx = blockIdx.x;                 // ((b*64 + c)*8 + hk)*4 + g
    const int g = idx & 3, hk = (idx >> 2) & 7, c = (idx >> 5) & 63, b = idx >> 11;
    const int h = hk * 4 + g;
    const int tokBase = b * 4096 + c * 64;
    __shared__ alignas(16) bf16_t q_lds[64 * 64];  // [tok][dk]
    __shared__ alignas(16) bf16_t k_lds[64 * 64];  // [tok][dk]
    __shared__ alignas(16) bf16_t vT[64 * 64];     // [dv][tok]
    __shared__ alignas(16) bf16_t zs[64 * 64];     // Zp [dv][dk], later scores [ti][tj]
    const int lane = threadIdx.x;
    const bf16_t* qg = proj + (size_t)tokBase * QKV + h * 64;
    const bf16_t* kg = proj + (size_t)tokBase * QKV + 2048 + hk * 64;
    const bf16_t* zg = Zp + (((size_t)(b * 32 + h)) * 64 + c) * 4096;
#pragma unroll
    for (int p = 0; p < 8; p++) {
        int row = p * 8 + (lane >> 3);
        int col = (lane & 7) * 8;
        gl_lds16(&qg[(size_t)row * QKV + col], &q_lds[p * 512 + lane * 8]);
        gl_lds16(&kg[(size_t)row * QKV + col], &k_lds[p * 512 + lane * 8]);
        gl_lds16(&zg[p * 512 + lane * 8],      &zs[p * 512 + lane * 8]);
    }
    const bf16_t* vg = proj + (size_t)tokBase * QKV + 2560 + hk * 64;
#pragma unroll
    for (int p = 0; p < 8; p++) {
        int tok = p * 8 + (lane >> 3);
        int d0  = (lane & 7) * 8;
        bf16x8 vv = *(const bf16x8*)&vg[(size_t)tok * QKV + d0];
#pragma unroll
        for (int e = 0; e < 8; e++) vT[(d0 + e) * 64 + tok] = vv[e];
    }
    __syncthreads();
    const int l15 = lane & 15, q8 = (lane >> 4) * 8, q4 = (lane >> 4) * 4;
    bf16x8 qf[2][4];
#pragma unroll
    for (int ks = 0; ks < 2; ks++)
#pragma unroll
        for (int mi = 0; mi < 4; mi++)
            qf[ks][mi] = *(const bf16x8*)&q_lds[(mi * 16 + l15) * 64 + ks * 32 + q8];
    // o = q @ S  (S[dk][dv] stored transposed in zs[dv][dk])
    f32x4 oacc[4][4] = {};
#pragma unroll
    for (int ks = 0; ks < 2; ks++) {
        bf16x8 zf[4];
#pragma unroll
        for (int nj = 0; nj < 4; nj++) zf[nj] = *(const bf16x8*)&zs[(nj * 16 + l15) * 64 + ks * 32 + q8];
#pragma unroll
        for (int mi = 0; mi < 4; mi++)
#pragma unroll
            for (int nj = 0; nj < 4; nj++)
                oacc[mi][nj] = MFMA16(qf[ks][mi], zf[nj], oacc[mi][nj]);
    }
    // scores = q @ k^T (only lower-triangle tiles)
    f32x4 sacc[4][4] = {};
#pragma unroll
    for (int ks = 0; ks < 2; ks++) {
        bf16x8 kf[4];
#pragma unroll
        for (int nj = 0; nj < 4; nj++) kf[nj] = *(const bf16x8*)&k_lds[(nj * 16 + l15) * 64 + ks * 32 + q8];
#pragma unroll
        for (int mi = 0; mi < 4; mi++)
#pragma unroll
            for (int nj = 0; nj < 4; nj++)
                if (mi >= nj) sacc[mi][nj] = MFMA16(qf[ks][mi], kf[nj], sacc[mi][nj]);
    }
    __syncthreads();
    // mask + write scores (bf16) into zs as [ti][tj]
#pragma unroll
    for (int mi = 0; mi < 4; mi++)
#pragma unroll
        for (int nj = 0; nj < 4; nj++)
#pragma unroll
            for (int r = 0; r < 4; r++) {
                int ti = mi * 16 + q4 + r, tj = nj * 16 + l15;
                float v = (ti >= tj) ? sacc[mi][nj][r] : 0.0f;
                zs[ti * 64 + tj] = (bf16_t)v;
            }
    __syncthreads();
    // o += scores @ v   (v[tj][dv] stored transposed in vT[dv][tj])
#pragma unroll
    for (int ks = 0; ks < 2; ks++) {
        bf16x8 sf[4], vf[4];
#pragma unroll
        for (int mi = 0; mi < 4; mi++) sf[mi] = *(const bf16x8*)&zs[(mi * 16 + l15) * 64 + ks * 32 + q8];
#pragma unroll
        for (int nj = 0; nj < 4; nj++) vf[nj] = *(const bf16x8*)&vT[(nj * 16 + l15) * 64 + ks * 32 + q8];
#pragma unroll
        for (int mi = 0; mi < 4; mi++)
#pragma unroll
            for (int nj = 0; nj < 4; nj++)
                oacc[mi][nj] = MFMA16(sf[mi], vf[nj], oacc[mi][nj]);
    }
    bf16_t* og = O + (size_t)tokBase * OUT_D + h * 64;
#pragma unroll
    for (int mi = 0; mi < 4; mi++)
#pragma unroll
        for (int nj = 0; nj < 4; nj++)
#pragma unroll
            for (int r = 0; r < 4; r++)
                og[(size_t)(mi * 16 + q4 + r) * OUT_D + nj * 16 + l15] = (bf16_t)oacc[mi][nj][r];
}

// ---------------- launcher ----------------
extern "C" void kernel_launch(void* const* d_in, const int* in_sizes, int n_in,
                              void* d_out, int out_size, void* d_ws, size_t ws_size,
                              hipStream_t stream) {
    const float* x     = (const float*)d_in[0];   // [2,4096,2048]
    const float* S0    = (const float*)d_in[1];   // [2, 32*64*64]
    const float* W_in  = (const float*)d_in[2];   // [2048,3072]
    const float* W_out = (const float*)d_in[3];   // [2048,2048]

    char* ws = (char*)d_ws;
    bf16_t* xb    = (bf16_t*)(ws + 0);            // 33.5 MB (dead after GEMM1)
    bf16_t* WinT  = (bf16_t*)(ws + 33554432);     // 12.6 MB
    bf16_t* WoutT = (bf16_t*)(ws + 46137344);     // 8.4 MB
    bf16_t* proj  = (bf16_t*)(ws + 54525952);     // 50.3 MB
    float*  Zc    = (float*) (ws + 104857600);    // 16.8 MB
    bf16_t* Zp    = (bf16_t*)(ws + 121634816);    // 33.5 MB
    bf16_t* Ob    = (bf16_t*)(ws + 0);            // aliases xb (xb dead by then)

    float* outMain  = (float*)d_out;
    float* outState = (float*)d_out + (size_t)S_TOT * OUT_D;  // +16777216

    // 1) x -> bf16
    cvt_f32_bf16<<<16384, 256, 0, stream>>>(x, xb);
    // 2) W_in^T, W_out^T (bf16)
    transpose_f32_bf16<<<dim3(48, 32), 256, 0, stream>>>(W_in, WinT, 2048, 3072);
    transpose_f32_bf16<<<dim3(32, 32), 256, 0, stream>>>(W_out, WoutT, 2048, 2048);
    // 3) proj = x @ W_in  (bf16 out)
    gemm_bt<1><<<dim3(24, 64), 256, 0, stream>>>(xb, WinT, proj, S_TOT, QKV, D_IN);
    // 4) per-chunk KV outer products
    chunk_kv<<<1024, 64, 0, stream>>>(proj, Zc);
    // 5) prefix states (+S0) and final-state output
    prefix_state<<<1024, 256, 0, stream>>>(Zc, S0, Zp, outState);
    // 6) per-chunk attention -> o (bf16)
    attn_chunk<<<4096, 64, 0, stream>>>(proj, Zp, Ob);
    // 7) out = o @ W_out (fp32 out, straight into d_out)
    gemm_bt<0><<<dim3(16, 64), 256, 0, stream>>>(Ob, WoutT, outMain, S_TOT, OUT_D, OUT_D);
}

// Round 2
// 414.394 us; speedup vs baseline: 1.0885x; 1.0885x over previous
//
#include <hip/hip_runtime.h>

typedef __bf16 bf16_t;
typedef __bf16 bf16x8 __attribute__((ext_vector_type(8)));
typedef __bf16 bf16x4 __attribute__((ext_vector_type(4)));
typedef float  f32x4  __attribute__((ext_vector_type(4)));

#define MFMA16(a,b,c) __builtin_amdgcn_mfma_f32_16x16x32_bf16((a),(b),(c),0,0,0)

__device__ __forceinline__ void gl_lds16(const void* g, void* l) {
    __builtin_amdgcn_global_load_lds(
        (__attribute__((address_space(1))) void*)(g),
        (__attribute__((address_space(3))) void*)(l),
        16, 0, 0);
}

// B=2 S=4096 D=2048 HQ=32 HK=HV=8 H=32 DK=DV=64 CHUNK=64 NC=64 QKV=3072 OUT=2048
static constexpr int S_TOT   = 8192;
static constexpr int D_IN    = 2048;
static constexpr int QKV     = 3072;
static constexpr int OUT_D   = 2048;
static constexpr int NCHUNK  = 64;

// ---------------- fp32 -> bf16 convert ----------------
__global__ __launch_bounds__(256)
void cvt_f32_bf16(const float* __restrict__ in, bf16_t* __restrict__ out) {
    int i = blockIdx.x * 256 + threadIdx.x;
    f32x4 v = ((const f32x4*)in)[i];
    bf16x4 o;
    o[0] = (bf16_t)v[0]; o[1] = (bf16_t)v[1]; o[2] = (bf16_t)v[2]; o[3] = (bf16_t)v[3];
    ((bf16x4*)out)[i] = o;
}

// ---------------- fp32 [R][C] -> bf16 [C][R] transpose ----------------
__global__ __launch_bounds__(256)
void transpose_f32_bf16(const float* __restrict__ in, bf16_t* __restrict__ out, int R, int C) {
    __shared__ float tile[64][65];
    const int t  = threadIdx.x;
    const int r0 = blockIdx.y * 64, c0 = blockIdx.x * 64;
#pragma unroll
    for (int p = 0; p < 4; p++) {
        int row = p * 16 + (t >> 4);
        int col = (t & 15) * 4;
        f32x4 v = *(const f32x4*)&in[(size_t)(r0 + row) * C + c0 + col];
        tile[row][col + 0] = v[0]; tile[row][col + 1] = v[1];
        tile[row][col + 2] = v[2]; tile[row][col + 3] = v[3];
    }
    __syncthreads();
#pragma unroll
    for (int p = 0; p < 4; p++) {
        int oc  = p * 16 + (t >> 4);
        int orr = (t & 15) * 4;
        bf16x4 v;
        v[0] = (bf16_t)tile[orr + 0][oc]; v[1] = (bf16_t)tile[orr + 1][oc];
        v[2] = (bf16_t)tile[orr + 2][oc]; v[3] = (bf16_t)tile[orr + 3][oc];
        *(bf16x4*)&out[(size_t)(c0 + oc) * R + r0 + orr] = v;
    }
}

// ---------------- GEMM: C[M][N] = A[M][K] * Bt[N][K]^T, 128x128 tile, BK=32 ----------------
// __launch_bounds__(256,4): force 4 blocks/CU so GEMM2's 1024-tile grid is fully
// resident in one pass (tail fix: at 3/CU, 1024 = 768+256 -> 0.67x efficiency).
template<int OUT_BF16>
__global__ __launch_bounds__(256, 4)
void gemm_bt(const bf16_t* __restrict__ A, const bf16_t* __restrict__ Bt,
             void* __restrict__ Cout, int M, int N, int K) {
    __shared__ alignas(16) bf16_t lA[128 * 32];
    __shared__ alignas(16) bf16_t lB[128 * 32];
    const int tid = threadIdx.x;
    const int m0 = blockIdx.y * 128;
    const int n0 = blockIdx.x * 128;
    const int w = tid >> 6, lane = tid & 63;
    const int wr = (w >> 1) * 64, wc = (w & 1) * 64;
    const int l15 = lane & 15, q8 = (lane >> 4) * 8, q4 = (lane >> 4) * 4;
    f32x4 acc[4][4] = {};
    const bf16_t* Ag = A + (size_t)(m0 + (tid >> 2)) * K + (tid & 3) * 8;
    const bf16_t* Bg = Bt + (size_t)(n0 + (tid >> 2)) * K + (tid & 3) * 8;
    const size_t rowStep = (size_t)64 * K;
    bf16_t* lA_t = lA + tid * 8;
    bf16_t* lB_t = lB + tid * 8;
    for (int k0 = 0; k0 < K; k0 += 32) {
        gl_lds16(Ag + k0,           lA_t);
        gl_lds16(Ag + k0 + rowStep, lA_t + 64 * 32);
        gl_lds16(Bg + k0,           lB_t);
        gl_lds16(Bg + k0 + rowStep, lB_t + 64 * 32);
        __syncthreads();
        bf16x8 bfr[4];
#pragma unroll
        for (int nj = 0; nj < 4; nj++) bfr[nj] = *(const bf16x8*)&lB[(wc + nj * 16 + l15) * 32 + q8];
#pragma unroll
        for (int mi = 0; mi < 4; mi++) {
            bf16x8 afr = *(const bf16x8*)&lA[(wr + mi * 16 + l15) * 32 + q8];
#pragma unroll
            for (int nj = 0; nj < 4; nj++)
                acc[mi][nj] = MFMA16(afr, bfr[nj], acc[mi][nj]);
        }
        __syncthreads();
    }
    if (OUT_BF16) {
        bf16_t* C = (bf16_t*)Cout;
#pragma unroll
        for (int mi = 0; mi < 4; mi++)
#pragma unroll
            for (int nj = 0; nj < 4; nj++)
#pragma unroll
                for (int r = 0; r < 4; r++)
                    C[(size_t)(m0 + wr + mi * 16 + q4 + r) * N + n0 + wc + nj * 16 + l15] =
                        (bf16_t)acc[mi][nj][r];
    } else {
        float* C = (float*)Cout;
#pragma unroll
        for (int mi = 0; mi < 4; mi++)
#pragma unroll
            for (int nj = 0; nj < 4; nj++)
#pragma unroll
                for (int r = 0; r < 4; r++)
                    C[(size_t)(m0 + wr + mi * 16 + q4 + r) * N + n0 + wc + nj * 16 + l15] =
                        acc[mi][nj][r];
    }
}

// ---------------- transpose k,v chunks: proj -> kT_g/vT_g [b][hk][c][d][tok] ----------------
__global__ __launch_bounds__(64)
void transpose_kv(const bf16_t* __restrict__ proj,
                  bf16_t* __restrict__ kT_g, bf16_t* __restrict__ vT_g) {
    const int idx = blockIdx.x;               // ((b*8+hk)*64 + c)
    const int c = idx & 63, hk = (idx >> 6) & 7, b = idx >> 9;
    const int tokBase = b * 4096 + c * 64;
    __shared__ float tile[64][65];
    const int lane = threadIdx.x;
#pragma unroll
    for (int which = 0; which < 2; which++) {
        const bf16_t* src = proj + (size_t)tokBase * QKV + 2048 + which * 512 + hk * 64;
        bf16_t* dst = (which ? vT_g : kT_g) + (size_t)idx * 4096;
#pragma unroll
        for (int p = 0; p < 8; p++) {
            int tok = p * 8 + (lane >> 3);
            int d0  = (lane & 7) * 8;
            bf16x8 v = *(const bf16x8*)&src[(size_t)tok * QKV + d0];
#pragma unroll
            for (int e = 0; e < 8; e++) tile[tok][d0 + e] = (float)v[e];
        }
        __syncthreads();
#pragma unroll
        for (int p = 0; p < 8; p++) {
            int dk = p * 8 + (lane >> 3);
            int t0 = (lane & 7) * 8;
            bf16x8 o;
#pragma unroll
            for (int e = 0; e < 8; e++) o[e] = (bf16_t)tile[t0 + e][dk];
            *(bf16x8*)&dst[dk * 64 + t0] = o;
        }
        __syncthreads();
    }
}

// ---------------- Zc[idx][dv][dk] = v^T k per chunk (frags straight from global) ----------------
__global__ __launch_bounds__(64)
void chunk_kv(const bf16_t* __restrict__ kT_g, const bf16_t* __restrict__ vT_g,
              float* __restrict__ Zc) {
    const int idx = blockIdx.x;
    const int lane = threadIdx.x;
    const int l15 = lane & 15, q8 = (lane >> 4) * 8, q4 = (lane >> 4) * 4;
    const bf16_t* vT = vT_g + (size_t)idx * 4096;   // [dv][tok]
    const bf16_t* kT = kT_g + (size_t)idx * 4096;   // [dk][tok]
    f32x4 acc[4][4] = {};
#pragma unroll
    for (int ks = 0; ks < 2; ks++) {
        bf16x8 af[4], bf_[4];
#pragma unroll
        for (int mi = 0; mi < 4; mi++) af[mi]  = *(const bf16x8*)&vT[(mi * 16 + l15) * 64 + ks * 32 + q8];
#pragma unroll
        for (int nj = 0; nj < 4; nj++) bf_[nj] = *(const bf16x8*)&kT[(nj * 16 + l15) * 64 + ks * 32 + q8];
#pragma unroll
        for (int mi = 0; mi < 4; mi++)
#pragma unroll
            for (int nj = 0; nj < 4; nj++)
                acc[mi][nj] = MFMA16(af[mi], bf_[nj], acc[mi][nj]);
    }
    float* zout = Zc + (size_t)idx * 4096;
#pragma unroll
    for (int mi = 0; mi < 4; mi++)
#pragma unroll
        for (int nj = 0; nj < 4; nj++)
#pragma unroll
            for (int r = 0; r < 4; r++)
                zout[(mi * 16 + q4 + r) * 64 + nj * 16 + l15] = acc[mi][nj][r];
}

// ---------------- prefix state (+S0 at front), emit bf16 prefixes + final state ----------------
__global__ __launch_bounds__(256)
void prefix_state(const float* __restrict__ Zc, const float* __restrict__ S0,
                  bf16_t* __restrict__ Zp, float* __restrict__ SfOut) {
    const int slice = blockIdx.x & 15;
    const int bh = blockIdx.x >> 4;
    const int h = bh & 31, b = bh >> 5;
    const int hk = h >> 2;
    const int e = slice * 256 + threadIdx.x;      // e = dv*64 + dk
    const int dv = e >> 6, dk = e & 63;
    float acc = S0[(size_t)b * 131072 + h * 4096 + dk * 64 + dv];   // S0[b][h][dk][dv]
    const float* zc = Zc + ((size_t)(b * 8 + hk) * 64) * 4096 + e;
    bf16_t* zp = Zp + ((size_t)(b * 32 + h) * 64) * 4096 + e;
    for (int c = 0; c < NCHUNK; c++) {
        zp[(size_t)c * 4096] = (bf16_t)acc;
        acc += zc[(size_t)c * 4096];
    }
    SfOut[(size_t)b * 131072 + h * 4096 + dk * 64 + dv] = acc;
}

// ---------------- attn: o = mask(q k^T) v + q * Zp^T, frags from global, LDS only for scores ----
__global__ __launch_bounds__(64)
void attn_chunk(const bf16_t* __restrict__ proj, const bf16_t* __restrict__ vT_g,
                const bf16_t* __restrict__ Zp, bf16_t* __restrict__ O) {
    const int idx = blockIdx.x;                 // ((b*64 + c)*8 + hk)*4 + g
    const int g = idx & 3, hk = (idx >> 2) & 7, c = (idx >> 5) & 63, b = idx >> 11;
    const int h = hk * 4 + g;
    const int tokBase = b * 4096 + c * 64;
    __shared__ alignas(16) bf16_t zs[64 * 64];     // masked scores [ti][tj]
    const int lane = threadIdx.x;
    const int l15 = lane & 15, q8 = (lane >> 4) * 8, q4 = (lane >> 4) * 4;
    const bf16_t* qrow  = proj + (size_t)tokBase * QKV + h * 64;            // [ti][dk]
    const bf16_t* krow  = proj + (size_t)tokBase * QKV + 2048 + hk * 64;    // [tj][dk]
    const bf16_t* zrow  = Zp + (((size_t)(b * 32 + h)) * 64 + c) * 4096;    // [dv][dk]
    const bf16_t* vTrow = vT_g + ((size_t)(b * 8 + hk) * 64 + c) * 4096;    // [dv][tok]

    bf16x8 qf[2][4];
#pragma unroll
    for (int ks = 0; ks < 2; ks++)
#pragma unroll
        for (int mi = 0; mi < 4; mi++)
            qf[ks][mi] = *(const bf16x8*)&qrow[(size_t)(mi * 16 + l15) * QKV + ks * 32 + q8];

    // o = q @ S (Zp holds S^T as [dv][dk])
    f32x4 oacc[4][4] = {};
#pragma unroll
    for (int ks = 0; ks < 2; ks++) {
        bf16x8 zf[4];
#pragma unroll
        for (int nj = 0; nj < 4; nj++) zf[nj] = *(const bf16x8*)&zrow[(nj * 16 + l15) * 64 + ks * 32 + q8];
#pragma unroll
        for (int mi = 0; mi < 4; mi++)
#pragma unroll
            for (int nj = 0; nj < 4; nj++)
                oacc[mi][nj] = MFMA16(qf[ks][mi], zf[nj], oacc[mi][nj]);
    }
    // scores = q @ k^T (lower-triangle tiles only)
    f32x4 sacc[4][4] = {};
#pragma unroll
    for (int ks = 0; ks < 2; ks++) {
        bf16x8 kf[4];
#pragma unroll
        for (int nj = 0; nj < 4; nj++) kf[nj] = *(const bf16x8*)&krow[(size_t)(nj * 16 + l15) * QKV + ks * 32 + q8];
#pragma unroll
        for (int mi = 0; mi < 4; mi++)
#pragma unroll
            for (int nj = 0; nj < 4; nj++)
                if (mi >= nj) sacc[mi][nj] = MFMA16(qf[ks][mi], kf[nj], sacc[mi][nj]);
    }
    // mask + store scores as bf16 [ti][tj]
#pragma unroll
    for (int mi = 0; mi < 4; mi++)
#pragma unroll
        for (int nj = 0; nj < 4; nj++)
#pragma unroll
            for (int r = 0; r < 4; r++) {
                int ti = mi * 16 + q4 + r, tj = nj * 16 + l15;
                float v = (ti >= tj) ? sacc[mi][nj][r] : 0.0f;
                zs[ti * 64 + tj] = (bf16_t)v;
            }
    __syncthreads();
    // o += scores @ v
#pragma unroll
    for (int ks = 0; ks < 2; ks++) {
        bf16x8 sf[4], vf[4];
#pragma unroll
        for (int mi = 0; mi < 4; mi++) sf[mi] = *(const bf16x8*)&zs[(mi * 16 + l15) * 64 + ks * 32 + q8];
#pragma unroll
        for (int nj = 0; nj < 4; nj++) vf[nj] = *(const bf16x8*)&vTrow[(nj * 16 + l15) * 64 + ks * 32 + q8];
#pragma unroll
        for (int mi = 0; mi < 4; mi++)
#pragma unroll
            for (int nj = 0; nj < 4; nj++)
                oacc[mi][nj] = MFMA16(sf[mi], vf[nj], oacc[mi][nj]);
    }
    bf16_t* og = O + (size_t)tokBase * OUT_D + h * 64;
#pragma unroll
    for (int mi = 0; mi < 4; mi++)
#pragma unroll
        for (int nj = 0; nj < 4; nj++)
#pragma unroll
            for (int r = 0; r < 4; r++)
                og[(size_t)(mi * 16 + q4 + r) * OUT_D + nj * 16 + l15] = (bf16_t)oacc[mi][nj][r];
}

// ---------------- launcher ----------------
extern "C" void kernel_launch(void* const* d_in, const int* in_sizes, int n_in,
                              void* d_out, int out_size, void* d_ws, size_t ws_size,
                              hipStream_t stream) {
    const float* x     = (const float*)d_in[0];
    const float* S0    = (const float*)d_in[1];
    const float* W_in  = (const float*)d_in[2];
    const float* W_out = (const float*)d_in[3];

    char* ws = (char*)d_ws;
    bf16_t* xb    = (bf16_t*)(ws + 0);            // 33.5 MB; dead after GEMM1
    bf16_t* kT_g  = (bf16_t*)(ws + 16777216);     // 8.4 MB, overlays xb tail (xb dead)
    bf16_t* WinT  = (bf16_t*)(ws + 33554432);     // 12.6 MB; dead after GEMM1
    bf16_t* vT_g  = (bf16_t*)(ws + 33554432);     // 8.4 MB, overlays WinT (WinT dead)
    bf16_t* WoutT = (bf16_t*)(ws + 46137344);     // 8.4 MB
    bf16_t* proj  = (bf16_t*)(ws + 54525952);     // 50.3 MB
    float*  Zc    = (float*) (ws + 104857600);    // 16.8 MB
    bf16_t* Zp    = (bf16_t*)(ws + 121634816);    // 33.5 MB
    bf16_t* Ob    = (bf16_t*)(ws + 0);            // aliases xb+kT_g (both dead by attn)

    float* outMain  = (float*)d_out;
    float* outState = (float*)d_out + (size_t)S_TOT * OUT_D;

    cvt_f32_bf16<<<16384, 256, 0, stream>>>(x, xb);
    transpose_f32_bf16<<<dim3(48, 32), 256, 0, stream>>>(W_in, WinT, 2048, 3072);
    transpose_f32_bf16<<<dim3(32, 32), 256, 0, stream>>>(W_out, WoutT, 2048, 2048);
    gemm_bt<1><<<dim3(24, 64), 256, 0, stream>>>(xb, WinT, proj, S_TOT, QKV, D_IN);
    transpose_kv<<<1024, 64, 0, stream>>>(proj, kT_g, vT_g);
    chunk_kv<<<1024, 64, 0, stream>>>(kT_g, vT_g, Zc);
    prefix_state<<<1024, 256, 0, stream>>>(Zc, S0, Zp, outState);
    attn_chunk<<<4096, 64, 0, stream>>>(proj, vT_g, Zp, Ob);
    gemm_bt<0><<<dim3(16, 64), 256, 0, stream>>>(Ob, WoutT, outMain, S_TOT, OUT_D, OUT_D);
}